// Round 18
// baseline (135.125 us; speedup 1.0000x reference)
//
#include <hip/hip_runtime.h>
#include <hip/hip_bf16.h>

#define NB 16
#define NQ 128
#define NK 512
#define DIN 256   // QS == KS == 256
#define NH 128
#define NDV 256

#define CSC 2.8853900817779268f   // 2*log2(e): tanh(x) = 1 - 2/(1 + 2^(CSC*x))
#define L2E 1.4426950408889634f   // log2(e)

// Projection v5: 640 blocks of 16 rows (10 waves/CU). Thread: h4 = tid&31 ->
// h = 4*h4..+3 ; rg = tid>>5 -> rows {rg*2, rg*2+1}; acc[2][4] = 8 fma per
// 16B W-load. 2-deep software pipeline on W. K path: transposed KPT store via
// padded LDS tile.
__global__ __launch_bounds__(256) void proj_both_kernel(
    const float* __restrict__ Q, const float* __restrict__ K,
    const float* __restrict__ Wq, const float* __restrict__ Wk,
    float* __restrict__ QP, float* __restrict__ KPT)
{
    __shared__ float Xl[16 * DIN];   // 16KB; reused as transpose tile (K path)
    const int tid = threadIdx.x;
    int blk = blockIdx.x;
    const float* X; const float* W;
    int b, r0, isq;
    if (blk < 128) { isq = 1; b = blk >> 3; r0 = (blk & 7) * 16;
                     X = Q + ((size_t)b * NQ + r0) * DIN; W = Wq; }
    else { blk -= 128; isq = 0; b = blk >> 5; r0 = (blk & 31) * 16;
           X = K + ((size_t)b * NK + r0) * DIN; W = Wk; }

    {   // stage 16 rows: 1024 float4, coalesced
        const float4* Xg = (const float4*)X;
        float4* Xs = (float4*)Xl;
        #pragma unroll
        for (int i = 0; i < 4; ++i) Xs[tid + 256 * i] = Xg[tid + 256 * i];
    }
    __syncthreads();

    const int h4 = tid & 31;          // h = 4*h4
    const int rg = tid >> 5;          // rows rg*2, rg*2+1
    const float4* Wv = (const float4*)W;   // index d*32 + h4

    float4 acc[2];
    #pragma unroll
    for (int r = 0; r < 2; ++r) { acc[r].x = 0.f; acc[r].y = 0.f; acc[r].z = 0.f; acc[r].w = 0.f; }

    // 2-deep prefetch pipeline over 64 groups of 4 d-rows
    float4 w0 = Wv[0 * 32 + h4], w1 = Wv[1 * 32 + h4], w2 = Wv[2 * 32 + h4], w3 = Wv[3 * 32 + h4];
    float4 n0 = Wv[4 * 32 + h4], n1 = Wv[5 * 32 + h4], n2 = Wv[6 * 32 + h4], n3 = Wv[7 * 32 + h4];
    for (int d = 0; d < DIN; d += 4) {
        const int dp = (d + 8 < DIN) ? d + 8 : 0;     // harmless tail re-load
        float4 m0 = Wv[(dp + 0) * 32 + h4];
        float4 m1 = Wv[(dp + 1) * 32 + h4];
        float4 m2 = Wv[(dp + 2) * 32 + h4];
        float4 m3 = Wv[(dp + 3) * 32 + h4];
        #pragma unroll
        for (int r = 0; r < 2; ++r) {
            float4 x = *(const float4*)&Xl[(rg * 2 + r) * DIN + d];  // broadcast
            acc[r].x += x.x * w0.x + x.y * w1.x + x.z * w2.x + x.w * w3.x;
            acc[r].y += x.x * w0.y + x.y * w1.y + x.z * w2.y + x.w * w3.y;
            acc[r].z += x.x * w0.z + x.y * w1.z + x.z * w2.z + x.w * w3.z;
            acc[r].w += x.x * w0.w + x.y * w1.w + x.z * w2.w + x.w * w3.w;
        }
        w0 = n0; w1 = n1; w2 = n2; w3 = n3;
        n0 = m0; n1 = m1; n2 = m2; n3 = m3;
    }
    #pragma unroll
    for (int r = 0; r < 2; ++r) {
        acc[r].x *= CSC; acc[r].y *= CSC; acc[r].z *= CSC; acc[r].w *= CSC;
    }

    if (isq) {
        #pragma unroll
        for (int r = 0; r < 2; ++r)
            *(float4*)&QP[((size_t)b * NQ + r0 + rg * 2 + r) * NH + 4 * h4] = acc[r];
    } else {
        float* T = Xl;                // [128 h][20] padded (20*4B % 16 == 0)
        __syncthreads();
        #pragma unroll
        for (int r = 0; r < 2; ++r) {
            T[(4 * h4 + 0) * 20 + rg * 2 + r] = acc[r].x;
            T[(4 * h4 + 1) * 20 + rg * 2 + r] = acc[r].y;
            T[(4 * h4 + 2) * 20 + rg * 2 + r] = acc[r].z;
            T[(4 * h4 + 3) * 20 + rg * 2 + r] = acc[r].w;
        }
        __syncthreads();
        #pragma unroll
        for (int i = 0; i < 2; ++i) {
            const int idx = tid + 256 * i;        // 0..511
            const int h = idx >> 2, c4 = idx & 3; // 4 float4 per h row
            float4 v = *(const float4*)&T[h * 20 + c4 * 4];
            *(float4*)&KPT[((size_t)b * NH + h) * NK + r0 + c4 * 4] = v;
        }
    }
}

// Fused scores + softmax + attn@V.  Block = (b, 4 q rows), 512 thr, grid 512.
// XCD swizzle (b = blk&15): KPT[b]+V[b] L2-resident (FETCH ~7MB measured).
// Scores: depth-4 kv register prefetch (covers ~250cy L2 latency); exp fused
// into scores phase. NO max-subtraction: |score'| <= sum|wv| ~ 11 << exp2
// range, so unnormalized softmax is exact (masked -> 0). 1/s folded into the
// final store. Out: wave w covers 64-k slice for all 4 rows, 2-stage reduce.
__global__ __launch_bounds__(512) void attn_fused_kernel(
    const float* __restrict__ QP, const float* __restrict__ KPT,
    const float* __restrict__ wv, const int* __restrict__ vlen,
    const float* __restrict__ V, float* __restrict__ OUT)
{
    __shared__ float qcl[4 * NH];        // 2KB   CSC-scaled q-proj
    __shared__ float wvl[NH];            // 0.5KB -2*wv
    __shared__ float sc[4][NK];          // 8KB   exp(scores)
    __shared__ float part[4][4][NDV];    // 16KB  [k-quarter][row][d]
    __shared__ float sinv[4];            // 1/rowsum
    const int tid = threadIdx.x;
    const int b  = blockIdx.x & 15;      // XCD-local batch
    const int q0 = (blockIdx.x >> 4) * 4;

    qcl[tid] = QP[((size_t)b * NQ + q0) * NH + tid];
    if (tid < NH) wvl[tid] = -2.0f * wv[tid];
    __syncthreads();

    int vl = vlen[b];
    vl = vl < 1 ? 1 : (vl > NK ? NK : vl);

    // ---- scores + exp: sc[r][k] = exp(score'(r,k)) or 0 if masked
    {
        const float* kb = KPT + (size_t)b * NH * NK + tid;
        float a0 = 0.f, a1 = 0.f, a2 = 0.f, a3 = 0.f;
        float c0 = kb[0 * NK], c1 = kb[1 * NK], c2 = kb[2 * NK], c3 = kb[3 * NK];
        for (int h = 0; h < NH; h += 4) {
            const int hp = (h + 4 < NH) ? h + 4 : 0;   // tail re-load, unused
            float p0 = kb[(size_t)(hp + 0) * NK];
            float p1 = kb[(size_t)(hp + 1) * NK];
            float p2 = kb[(size_t)(hp + 2) * NK];
            float p3 = kb[(size_t)(hp + 3) * NK];
            #pragma unroll
            for (int j = 0; j < 4; ++j) {
                const float kv = (j == 0) ? c0 : (j == 1) ? c1 : (j == 2) ? c2 : c3;
                const float wq = wvl[h + j];                 // broadcast
                float e0 = __builtin_amdgcn_exp2f(qcl[0 * NH + h + j] + kv);
                float e1 = __builtin_amdgcn_exp2f(qcl[1 * NH + h + j] + kv);
                float e2 = __builtin_amdgcn_exp2f(qcl[2 * NH + h + j] + kv);
                float e3 = __builtin_amdgcn_exp2f(qcl[3 * NH + h + j] + kv);
                a0 += wq * __builtin_amdgcn_rcpf(e0 + 1.0f);
                a1 += wq * __builtin_amdgcn_rcpf(e1 + 1.0f);
                a2 += wq * __builtin_amdgcn_rcpf(e2 + 1.0f);
                a3 += wq * __builtin_amdgcn_rcpf(e3 + 1.0f);
            }
            c0 = p0; c1 = p1; c2 = p2; c3 = p3;
        }
        const bool vld = (tid < vl);
        sc[0][tid] = vld ? __builtin_amdgcn_exp2f(a0 * L2E) : 0.f;
        sc[1][tid] = vld ? __builtin_amdgcn_exp2f(a1 * L2E) : 0.f;
        sc[2][tid] = vld ? __builtin_amdgcn_exp2f(a2 * L2E) : 0.f;
        sc[3][tid] = vld ? __builtin_amdgcn_exp2f(a3 * L2E) : 0.f;
    }
    __syncthreads();

    // ---- row sums: wave w (0..3) sums row w
    const int w = tid >> 6, lane = tid & 63;
    if (w < 4) {
        float s = 0.f;
        #pragma unroll
        for (int i = 0; i < 8; ++i) s += sc[w][lane + 64 * i];
        #pragma unroll
        for (int off = 32; off; off >>= 1) s += __shfl_xor(s, off, 64);
        if (lane == 0) sinv[w] = __builtin_amdgcn_rcpf(s);   // s >= 2^-16 > 0
    }
    __syncthreads();

    // ---- out partials: wave w covers k in [w*64, w*64+64) for ALL 4 rows
    float4 o[4];
    #pragma unroll
    for (int r = 0; r < 4; ++r) { o[r].x = 0.f; o[r].y = 0.f; o[r].z = 0.f; o[r].w = 0.f; }
    {
        const float* vb = V + (size_t)b * NK * NDV + lane * 4;
        const int kb0 = w * 64;
        #pragma unroll 4
        for (int kk = 0; kk < 64; ++kk) {
            const int k = kb0 + kk;
            float4 v4 = *(const float4*)(vb + (size_t)k * NDV);   // 1KB/wave coalesced
            float p0 = sc[0][k], p1 = sc[1][k], p2 = sc[2][k], p3 = sc[3][k];
            o[0].x += p0 * v4.x; o[0].y += p0 * v4.y; o[0].z += p0 * v4.z; o[0].w += p0 * v4.w;
            o[1].x += p1 * v4.x; o[1].y += p1 * v4.y; o[1].z += p1 * v4.z; o[1].w += p1 * v4.w;
            o[2].x += p2 * v4.x; o[2].y += p2 * v4.y; o[2].z += p2 * v4.z; o[2].w += p2 * v4.w;
            o[3].x += p3 * v4.x; o[3].y += p3 * v4.y; o[3].z += p3 * v4.z; o[3].w += p3 * v4.w;
        }
    }
    if (w >= 4) {        // stage 1: waves 4-7 write partials
        #pragma unroll
        for (int r = 0; r < 4; ++r) *(float4*)&part[w - 4][r][lane * 4] = o[r];
    }
    __syncthreads();
    if (w < 4) {         // stage 2: waves 0-3 pair-combine
        #pragma unroll
        for (int r = 0; r < 4; ++r) {
            float4 t = *(const float4*)&part[w][r][lane * 4];
            o[r].x += t.x; o[r].y += t.y; o[r].z += t.z; o[r].w += t.w;
            *(float4*)&part[w][r][lane * 4] = o[r];
        }
    }
    __syncthreads();
    if (tid < 256) {     // stage 3: sum 4 k-quarters, scale by 1/rowsum, store
        const int r = tid >> 6, d4 = tid & 63;
        const float iv = sinv[r];
        float4 s = {0.f, 0.f, 0.f, 0.f};
        #pragma unroll
        for (int p = 0; p < 4; ++p) {
            float4 q = *(const float4*)&part[p][r][d4 * 4];
            s.x += q.x; s.y += q.y; s.z += q.z; s.w += q.w;
        }
        s.x *= iv; s.y *= iv; s.z *= iv; s.w *= iv;
        *(float4*)&OUT[((size_t)b * NQ + q0 + r) * NDV + d4 * 4] = s;
    }
}

extern "C" void kernel_launch(void* const* d_in, const int* in_sizes, int n_in,
                              void* d_out, int out_size, void* d_ws, size_t ws_size,
                              hipStream_t stream) {
    const float* queries = (const float*)d_in[0];  // [16,128,256] f32
    const float* keys    = (const float*)d_in[1];  // [16,512,256] f32
    const float* values  = (const float*)d_in[2];  // [16,512,256] f32
    const int*   vlen    = (const int*)d_in[3];    // [16] int32
    const float* Wq      = (const float*)d_in[4];  // [256,128] f32
    const float* Wk      = (const float*)d_in[5];  // [256,128] f32
    const float* wv      = (const float*)d_in[6];  // [128] f32
    float* out           = (float*)d_out;          // [16,128,256] f32

    float* qp  = (float*)d_ws;                     // QP  [16][128][128] = 1MB (CSC-scaled)
    float* kpt = qp + (size_t)NB * NQ * NH;        // KPT [16][128][512] = 4MB (CSC-scaled, transposed)

    proj_both_kernel<<<128 + 512, 256, 0, stream>>>(queries, keys, Wq, Wk, qp, kpt);
    attn_fused_kernel<<<NB * 32, 512, 0, stream>>>(qp, kpt, wv, vlen, values, out);
}